// Round 6
// baseline (110.579 us; speedup 1.0000x reference)
//
#include <hip/hip_runtime.h>
#include <cmath>

// NSAB_5420248727612: per-row sigmoid-moment reductions + 2x2 Newton solve.
// B=2048 rows, N=8192 cols fp32. Memory-bound: 64 MiB read; floor ~10.7 us.
//
// Round-6 = round-4 structure (best verified: absmax 1.5e-5) + nontemporal
// loads on the x stream. Post-mortem ledger:
//  * r1: __launch_bounds__(256,6) VGPR cap -> accumulator spills. Never cap.
//  * r2: 4-load cluster drained between clusters -> no gain, regs up.
//  * r3: VALU trim 22->18 ops/elem == r0 -> not VALU-issue-bound.
//  * r4: burst-8 loads per thread: kernel 22.2 -> 18.7 us. Kept.
//  * r5: sustained 8-deep window, wave-per-row: SAME 18.7 us (schedule
//    shape is not the limiter) and absmax 7.6e-6 -> 0.5 (128-elem fp32
//    chains amplified by the ill-conditioned 2x2 solve). Reverted.
//  * r6: nt loads (x is single-pass streaming; skip L2/L3 allocation).
// Accuracy: keep 32-elem fp32 chains + 6-level tree + 4-way f64 combine.

#define THREADS 256

typedef float f32x4 __attribute__((ext_vector_type(4)));

__device__ __forceinline__ float fast_exp2(float t) {
#if __has_builtin(__builtin_amdgcn_exp2f)
    return __builtin_amdgcn_exp2f(t);   // v_exp_f32
#else
    return exp2f(t);
#endif
}

__device__ __forceinline__ float fast_rcp(float t) {
#if __has_builtin(__builtin_amdgcn_rcpf)
    return __builtin_amdgcn_rcpf(t);    // v_rcp_f32 (~1 ulp)
#else
    return 1.0f / t;
#endif
}

// f64 epilogue: S[12] = monomial row sums
// (A1..A4 = sum s^k, B1..B4 = sum s^k x, C1..C4 = sum s^k x^2).
__device__ __forceinline__ void nsab_epilogue(
    const double* S, int N, double mv, double vv,
    float* __restrict__ out, int B, int row)
{
    const double invN = 1.0 / (double)N;
    const double M1 = S[0] * invN, M2 = S[1] * invN;
    const double M3 = S[2] * invN, M4 = S[3] * invN;
    const double X1 = S[4] * invN, X2 = S[5] * invN;
    const double X3 = S[6] * invN, X4 = S[7] * invN;
    const double Y1 = S[8] * invN, Y2 = S[9] * invN;
    const double Y3 = S[10] * invN, Y4 = S[11] * invN;

    const double fm       = M1;
    const double mff      = M2;
    const double dem_db   = M1 - M2;                        // mean(sp)
    const double dem_da   = X1 - X2;                        // mean(sp x)
    const double d2em_db2 = M1 - 3.0 * M2 + 2.0 * M3;       // mean(spp)
    const double d2em_dab = X1 - 3.0 * X2 + 2.0 * X3;       // mean(spp x)
    const double d2em_da2 = Y1 - 3.0 * Y2 + 2.0 * Y3;       // mean(spp x^2)
    const double m_fdfb   = M2 - M3;                        // mean(s sp)
    const double m_fdfa   = X2 - X3;                        // mean(s sp x)
    const double m_w      = 2.0 * M2 - 5.0 * M3 + 3.0 * M4; // mean(w)
    const double m_wx     = 2.0 * X2 - 5.0 * X3 + 3.0 * X4; // mean(w x)
    const double m_wx2    = 2.0 * Y2 - 5.0 * Y3 + 3.0 * Y4; // mean(w x^2)

    const double em = fm - mv;
    const double ev = mff - fm * fm - vv;
    const double dev_da = 2.0 * (m_fdfa - fm * dem_da);
    const double dev_db = 2.0 * (m_fdfb - fm * dem_db);
    const double d2ev_da2 = 2.0 * (m_wx2 - dem_da * dem_da - fm * d2em_da2);
    const double d2ev_dab = 2.0 * (m_wx  - dem_da * dem_db - fm * d2em_dab);
    const double d2ev_db2 = 2.0 * (m_w   - dem_db * dem_db - fm * d2em_db2);

    const double dl_da = 2.0 * (em * dem_da + ev * dev_da);
    const double dl_db = 2.0 * (em * dem_db + ev * dev_db);
    const double d2l_da2 = 2.0 * (dem_da * dem_da + em * d2em_da2
                                + dev_da * dev_da + ev * d2ev_da2);
    const double d2l_dab = 2.0 * (dem_da * dem_db + em * d2em_dab
                                + dev_da * dev_db + ev * d2ev_dab);
    const double d2l_db2 = 2.0 * (dem_db * dem_db + em * d2em_db2
                                + dev_db * dev_db + ev * d2ev_db2);

    const double den = d2l_da2 * d2l_db2 - d2l_dab * d2l_dab;
    const double na = (dl_da * d2l_db2 - dl_db * d2l_dab) / den;
    const double nb = (dl_db * d2l_da2 - dl_da * d2l_dab) / den;

    out[row]     = (float)na;
    out[B + row] = (float)nb;
}

// Per-element update: 18 VALU + 2 transcendental.
#define NSAB_PROC(xx_)  do {                                        \
    const float xx = (xx_);                                         \
    const float e  = fast_exp2(fmaf(c1, xx, c0));                   \
    const float s  = fast_rcp(1.0f + e);                            \
    const float s2 = s * s;                                         \
    const float s3 = s2 * s;                                        \
    const float s4 = s2 * s2;                                       \
    const float x2 = xx * xx;                                       \
    A1 += s;  A2 += s2;  A3 += s3;  A4 += s4;                       \
    B1 = fmaf(s,  xx, B1);  B2 = fmaf(s2, xx, B2);                  \
    B3 = fmaf(s3, xx, B3);  B4 = fmaf(s4, xx, B4);                  \
    C1 = fmaf(s,  x2, C1);  C2 = fmaf(s2, x2, C2);                  \
    C3 = fmaf(s3, x2, C3);  C4 = fmaf(s4, x2, C4);                  \
} while (0)

#define NSAB_PROC4(v)  do {                                         \
    NSAB_PROC((v).x); NSAB_PROC((v).y);                             \
    NSAB_PROC((v).z); NSAB_PROC((v).w);                             \
} while (0)

__global__ __launch_bounds__(THREADS) void nsab_kernel(
    const float* __restrict__ x,
    const float* __restrict__ a,
    const float* __restrict__ b,
    const float* __restrict__ meanp,
    const float* __restrict__ varp,
    float* __restrict__ out,
    int B, int N)
{
    const int row = blockIdx.x;
    const int tid = threadIdx.x;

    const float av = a[row];
    const float bv = b[row];
    // s = 1/(1+exp(-(a*x+b))) = 1/(1+exp2(c1*x+c0))
    const float LOG2E = 1.4426950408889634f;
    const float c1 = -av * LOG2E;
    const float c0 = -bv * LOG2E;

    const f32x4* __restrict__ xr = (const f32x4*)(x + (size_t)row * (size_t)N);
    const int nvec = N >> 2;

    // 12 monomial sums.
    float A1 = 0.f, A2 = 0.f, A3 = 0.f, A4 = 0.f;
    float B1 = 0.f, B2 = 0.f, B3 = 0.f, B4 = 0.f;
    float C1 = 0.f, C2 = 0.f, C3 = 0.f, C4 = 0.f;

    if (nvec == 8 * THREADS) {
        // Fast path (N=8192): 8 independent nt loads issued back-to-back;
        // 8 KB outstanding per wave; incremental vmcnt drain during compute.
        // nt: single-pass stream, skip L2/L3 allocation.
        const f32x4* p = xr + tid;
        f32x4 v0 = __builtin_nontemporal_load(p + 0 * THREADS);
        f32x4 v1 = __builtin_nontemporal_load(p + 1 * THREADS);
        f32x4 v2 = __builtin_nontemporal_load(p + 2 * THREADS);
        f32x4 v3 = __builtin_nontemporal_load(p + 3 * THREADS);
        f32x4 v4 = __builtin_nontemporal_load(p + 4 * THREADS);
        f32x4 v5 = __builtin_nontemporal_load(p + 5 * THREADS);
        f32x4 v6 = __builtin_nontemporal_load(p + 6 * THREADS);
        f32x4 v7 = __builtin_nontemporal_load(p + 7 * THREADS);
        NSAB_PROC4(v0); NSAB_PROC4(v1); NSAB_PROC4(v2); NSAB_PROC4(v3);
        NSAB_PROC4(v4); NSAB_PROC4(v5); NSAB_PROC4(v6); NSAB_PROC4(v7);
    } else {
        // Generic fallback: 1-ahead pipeline.
        int i = tid;
        if (i < nvec) {
            f32x4 cur = xr[i];
            #pragma unroll 1
            for (; i + THREADS < nvec; i += THREADS) {
                f32x4 nxt = xr[i + THREADS];
                NSAB_PROC4(cur);
                cur = nxt;
            }
            NSAB_PROC4(cur);
        }
    }

    float acc[12] = {A1, A2, A3, A4, B1, B2, B3, B4, C1, C2, C3, C4};

    // 64-lane wave butterfly reduce
    #pragma unroll
    for (int k = 0; k < 12; ++k) {
        float v = acc[k];
        #pragma unroll
        for (int off = 32; off > 0; off >>= 1)
            v += __shfl_down(v, off, 64);
        acc[k] = v;
    }

    __shared__ float part[THREADS / 64][12];
    const int wave = tid >> 6;
    const int lane = tid & 63;
    if (lane == 0) {
        #pragma unroll
        for (int k = 0; k < 12; ++k) part[wave][k] = acc[k];
    }
    __syncthreads();

    if (tid == 0) {
        double S[12];
        #pragma unroll
        for (int k = 0; k < 12; ++k)
            S[k] = (double)part[0][k] + (double)part[1][k]
                 + (double)part[2][k] + (double)part[3][k];
        nsab_epilogue(S, N, (double)meanp[row], (double)varp[row], out, B, row);
    }
}

extern "C" void kernel_launch(void* const* d_in, const int* in_sizes, int n_in,
                              void* d_out, int out_size, void* d_ws, size_t ws_size,
                              hipStream_t stream) {
    const float* x    = (const float*)d_in[0];
    const float* a    = (const float*)d_in[1];
    const float* b    = (const float*)d_in[2];
    const float* mean = (const float*)d_in[3];
    const float* var  = (const float*)d_in[4];
    const int B = in_sizes[1];            // a is (B,1)
    const int N = in_sizes[0] / B;        // x is (B,N)
    float* out = (float*)d_out;

    nsab_kernel<<<dim3(B), dim3(THREADS), 0, stream>>>(x, a, b, mean, var, out, B, N);
}

// Round 7
// 101.618 us; speedup vs baseline: 1.0882x; 1.0882x over previous
//
#include <hip/hip_runtime.h>
#include <cmath>

// NSAB_5420248727612: per-row sigmoid-moment reductions + 2x2 Newton solve.
// B=2048 rows, N=8192 cols fp32. Memory-bound: 64 MiB read; floor ~10.7 us.
//
// FINAL (round-7) = round-4 structure, the measured best (100.7 us composite,
// kernel ~18.7 us, absmax 1.5e-5). Full ablation ledger:
//  * r1: __launch_bounds__(256,6) VGPR cap -> accumulator spills (WRITE_SIZE
//    236 MiB scratch). Never set the min-waves arg on a ~70-VGPR live set.
//  * r2: 4-load cluster -> drained between clusters + occupancy step; -15%.
//  * r3: VALU trim 22->18 ops/elem -> null; not VALU-issue-bound.
//  * r4: burst-8 independent loads/thread (8 KB/wave in flight) -> +16%. KEPT.
//  * r5: sustained 8-deep rolling window, wave-per-row, no barriers -> same
//    perf as r4 (schedule shape not the limiter); absmax 0.5 (128-elem fp32
//    chains through the ill-conditioned 2x2 solve). Reverted.
//  * r6: __builtin_nontemporal_load on x -> kernel +53% (nt demotes the
//    read path on gfx950). Never nt this stream.
// Remaining dur_us is ~82 us of harness fillBuffer re-poison (2 x 41 us at
// ~82% peak HBM) + ~18.7 us kernel ~= 3.9 TB/s effective single-pass read
// with 2 transcendentals/elem. Ceiling declared: every lever ablated.

#define THREADS 256

typedef float f32x4 __attribute__((ext_vector_type(4)));

__device__ __forceinline__ float fast_exp2(float t) {
#if __has_builtin(__builtin_amdgcn_exp2f)
    return __builtin_amdgcn_exp2f(t);   // v_exp_f32
#else
    return exp2f(t);
#endif
}

__device__ __forceinline__ float fast_rcp(float t) {
#if __has_builtin(__builtin_amdgcn_rcpf)
    return __builtin_amdgcn_rcpf(t);    // v_rcp_f32 (~1 ulp)
#else
    return 1.0f / t;
#endif
}

// f64 epilogue: S[12] = monomial row sums
// (A1..A4 = sum s^k, B1..B4 = sum s^k x, C1..C4 = sum s^k x^2).
__device__ __forceinline__ void nsab_epilogue(
    const double* S, int N, double mv, double vv,
    float* __restrict__ out, int B, int row)
{
    const double invN = 1.0 / (double)N;
    const double M1 = S[0] * invN, M2 = S[1] * invN;
    const double M3 = S[2] * invN, M4 = S[3] * invN;
    const double X1 = S[4] * invN, X2 = S[5] * invN;
    const double X3 = S[6] * invN, X4 = S[7] * invN;
    const double Y1 = S[8] * invN, Y2 = S[9] * invN;
    const double Y3 = S[10] * invN, Y4 = S[11] * invN;

    // Exact reconstruction of the reference means:
    //   sp  = s - s^2 ; spp = s - 3s^2 + 2s^3 ; s*sp = s^2 - s^3
    //   w   = sp^2 + s*spp = 2s^2 - 5s^3 + 3s^4
    const double fm       = M1;
    const double mff      = M2;
    const double dem_db   = M1 - M2;                        // mean(sp)
    const double dem_da   = X1 - X2;                        // mean(sp x)
    const double d2em_db2 = M1 - 3.0 * M2 + 2.0 * M3;       // mean(spp)
    const double d2em_dab = X1 - 3.0 * X2 + 2.0 * X3;       // mean(spp x)
    const double d2em_da2 = Y1 - 3.0 * Y2 + 2.0 * Y3;       // mean(spp x^2)
    const double m_fdfb   = M2 - M3;                        // mean(s sp)
    const double m_fdfa   = X2 - X3;                        // mean(s sp x)
    const double m_w      = 2.0 * M2 - 5.0 * M3 + 3.0 * M4; // mean(w)
    const double m_wx     = 2.0 * X2 - 5.0 * X3 + 3.0 * X4; // mean(w x)
    const double m_wx2    = 2.0 * Y2 - 5.0 * Y3 + 3.0 * Y4; // mean(w x^2)

    const double em = fm - mv;
    const double ev = mff - fm * fm - vv;
    const double dev_da = 2.0 * (m_fdfa - fm * dem_da);
    const double dev_db = 2.0 * (m_fdfb - fm * dem_db);
    const double d2ev_da2 = 2.0 * (m_wx2 - dem_da * dem_da - fm * d2em_da2);
    const double d2ev_dab = 2.0 * (m_wx  - dem_da * dem_db - fm * d2em_dab);
    const double d2ev_db2 = 2.0 * (m_w   - dem_db * dem_db - fm * d2em_db2);

    const double dl_da = 2.0 * (em * dem_da + ev * dev_da);
    const double dl_db = 2.0 * (em * dem_db + ev * dev_db);
    const double d2l_da2 = 2.0 * (dem_da * dem_da + em * d2em_da2
                                + dev_da * dev_da + ev * d2ev_da2);
    const double d2l_dab = 2.0 * (dem_da * dem_db + em * d2em_dab
                                + dev_da * dev_db + ev * d2ev_dab);
    const double d2l_db2 = 2.0 * (dem_db * dem_db + em * d2em_db2
                                + dev_db * dev_db + ev * d2ev_db2);

    const double den = d2l_da2 * d2l_db2 - d2l_dab * d2l_dab;
    const double na = (dl_da * d2l_db2 - dl_db * d2l_dab) / den;
    const double nb = (dl_db * d2l_da2 - dl_da * d2l_dab) / den;

    out[row]     = (float)na;
    out[B + row] = (float)nb;
}

// Per-element update: 18 VALU + 2 transcendental.
#define NSAB_PROC(xx_)  do {                                        \
    const float xx = (xx_);                                         \
    const float e  = fast_exp2(fmaf(c1, xx, c0));                   \
    const float s  = fast_rcp(1.0f + e);                            \
    const float s2 = s * s;                                         \
    const float s3 = s2 * s;                                        \
    const float s4 = s2 * s2;                                       \
    const float x2 = xx * xx;                                       \
    A1 += s;  A2 += s2;  A3 += s3;  A4 += s4;                       \
    B1 = fmaf(s,  xx, B1);  B2 = fmaf(s2, xx, B2);                  \
    B3 = fmaf(s3, xx, B3);  B4 = fmaf(s4, xx, B4);                  \
    C1 = fmaf(s,  x2, C1);  C2 = fmaf(s2, x2, C2);                  \
    C3 = fmaf(s3, x2, C3);  C4 = fmaf(s4, x2, C4);                  \
} while (0)

#define NSAB_PROC4(v)  do {                                         \
    NSAB_PROC((v).x); NSAB_PROC((v).y);                             \
    NSAB_PROC((v).z); NSAB_PROC((v).w);                             \
} while (0)

__global__ __launch_bounds__(THREADS) void nsab_kernel(
    const float* __restrict__ x,
    const float* __restrict__ a,
    const float* __restrict__ b,
    const float* __restrict__ meanp,
    const float* __restrict__ varp,
    float* __restrict__ out,
    int B, int N)
{
    const int row = blockIdx.x;
    const int tid = threadIdx.x;

    const float av = a[row];
    const float bv = b[row];
    // s = 1/(1+exp(-(a*x+b))) = 1/(1+exp2(c1*x+c0))
    const float LOG2E = 1.4426950408889634f;
    const float c1 = -av * LOG2E;
    const float c0 = -bv * LOG2E;

    const f32x4* __restrict__ xr = (const f32x4*)(x + (size_t)row * (size_t)N);
    const int nvec = N >> 2;

    // 12 monomial sums.
    float A1 = 0.f, A2 = 0.f, A3 = 0.f, A4 = 0.f;
    float B1 = 0.f, B2 = 0.f, B3 = 0.f, B4 = 0.f;
    float C1 = 0.f, C2 = 0.f, C3 = 0.f, C4 = 0.f;

    if (nvec == 8 * THREADS) {
        // Fast path (N=8192): 8 independent loads issued back-to-back;
        // 8 KB outstanding per wave; incremental vmcnt drain during compute.
        const f32x4* p = xr + tid;
        f32x4 v0 = p[0 * THREADS];
        f32x4 v1 = p[1 * THREADS];
        f32x4 v2 = p[2 * THREADS];
        f32x4 v3 = p[3 * THREADS];
        f32x4 v4 = p[4 * THREADS];
        f32x4 v5 = p[5 * THREADS];
        f32x4 v6 = p[6 * THREADS];
        f32x4 v7 = p[7 * THREADS];
        NSAB_PROC4(v0); NSAB_PROC4(v1); NSAB_PROC4(v2); NSAB_PROC4(v3);
        NSAB_PROC4(v4); NSAB_PROC4(v5); NSAB_PROC4(v6); NSAB_PROC4(v7);
    } else {
        // Generic fallback: 1-ahead pipeline.
        int i = tid;
        if (i < nvec) {
            f32x4 cur = xr[i];
            #pragma unroll 1
            for (; i + THREADS < nvec; i += THREADS) {
                f32x4 nxt = xr[i + THREADS];
                NSAB_PROC4(cur);
                cur = nxt;
            }
            NSAB_PROC4(cur);
        }
    }

    float acc[12] = {A1, A2, A3, A4, B1, B2, B3, B4, C1, C2, C3, C4};

    // 64-lane wave butterfly reduce
    #pragma unroll
    for (int k = 0; k < 12; ++k) {
        float v = acc[k];
        #pragma unroll
        for (int off = 32; off > 0; off >>= 1)
            v += __shfl_down(v, off, 64);
        acc[k] = v;
    }

    __shared__ float part[THREADS / 64][12];
    const int wave = tid >> 6;
    const int lane = tid & 63;
    if (lane == 0) {
        #pragma unroll
        for (int k = 0; k < 12; ++k) part[wave][k] = acc[k];
    }
    __syncthreads();

    if (tid == 0) {
        double S[12];
        #pragma unroll
        for (int k = 0; k < 12; ++k)
            S[k] = (double)part[0][k] + (double)part[1][k]
                 + (double)part[2][k] + (double)part[3][k];
        nsab_epilogue(S, N, (double)meanp[row], (double)varp[row], out, B, row);
    }
}

extern "C" void kernel_launch(void* const* d_in, const int* in_sizes, int n_in,
                              void* d_out, int out_size, void* d_ws, size_t ws_size,
                              hipStream_t stream) {
    const float* x    = (const float*)d_in[0];
    const float* a    = (const float*)d_in[1];
    const float* b    = (const float*)d_in[2];
    const float* mean = (const float*)d_in[3];
    const float* var  = (const float*)d_in[4];
    const int B = in_sizes[1];            // a is (B,1)
    const int N = in_sizes[0] / B;        // x is (B,N)
    float* out = (float*)d_out;

    nsab_kernel<<<dim3(B), dim3(THREADS), 0, stream>>>(x, a, b, mean, var, out, B, N);
}